// Round 1
// 167.806 us; speedup vs baseline: 1.0262x; 1.0262x over previous
//
#include <hip/hip_runtime.h>
#include <math.h>

#define B_ 8
#define L_ 1024
#define K_ 1024
#define D_ 128
#define S_ 16
#define DS_ (D_ * S_)
#define NIT_ 16          // full contraction, BK=64

typedef short bf16x8 __attribute__((ext_vector_type(8)));
typedef float f32x4 __attribute__((ext_vector_type(4)));
typedef __attribute__((address_space(1))) const unsigned int gu32;
typedef __attribute__((address_space(3))) unsigned int lu32;

__device__ inline unsigned short f2bf(float f) {
    unsigned int u = __float_as_uint(f);
    u = (u + 0x7fffu + ((u >> 16) & 1u)) >> 16;   // RNE
    return (unsigned short)u;
}
__device__ inline float bf2f(unsigned short h) {
    return __uint_as_float(((unsigned int)h) << 16);
}

// B operands (u', G) stored PRE-SWIZZLED in glds consumption order:
// idx = ((((b*32 + ct)*4 + q)*128 + n)*8 + i), c = ct*32 + q*8 + i.
__device__ inline size_t bswz(int b, int c, int n) {
    return ((((size_t)b * 32 + (c >> 5)) * 4 + ((c >> 3) & 3)) * 128 + n) * 8;
}

// ---------------------------------------------------------------------------
// Fused: params (blocks 0-7) + rownorm + BN + in-proj + swizzled bf16 hi/lo u.
// 16 rows/block, 512 blocks.  (unchanged)
// ---------------------------------------------------------------------------
__global__ __launch_bounds__(256) void k_pre(
    const float* __restrict__ E, const float* __restrict__ x,
    const float* __restrict__ g, const float* __restrict__ beta,
    const float* __restrict__ mean, const float* __restrict__ var,
    const float* __restrict__ W_in, const float* __restrict__ b_in,
    const float* __restrict__ log_Delta, const float* __restrict__ Bp,
    const float* __restrict__ Cp, const float* __restrict__ log_A_real,
    const float* __restrict__ A_imag,
    float* __restrict__ rn_out, float* __restrict__ par,
    unsigned short* __restrict__ uswH, unsigned short* __restrict__ uswL) {
    __shared__ float xb[16][128];
    __shared__ float rsum[16];
    __shared__ float rnS[16];
    int bx = blockIdx.x;
    int row0 = bx * 16;
    int t = threadIdx.x;
    // --- params (double precision), spread over blocks 0-7 ---
    if (bx < 8) {
        int i = bx * 256 + t;                // i = d*S + s
        int d = i >> 4, s = i & 15;
        double delta = exp((double)log_Delta[d]);
        double Are = -exp((double)log_A_real[i]);
        double Aim = (double)A_imag[i];
        double mag = exp(-1e-3 + delta * Are);
        double ang = delta * Aim;
        int o = s * D_ + d;
        par[o]           = (float)(mag * cos(ang));
        par[DS_ + o]     = (float)(mag * sin(ang));
        par[2 * DS_ + o] = (float)(delta * (double)Bp[i] * (double)Cp[i]);
    }
    // --- row norms: 16 threads per row ---
    {
        int r = t >> 4, tt = t & 15;
        const float4* Ep = (const float4*)(E + (size_t)(row0 + r) * K_);
        float s = 0.f;
        #pragma unroll
        for (int i = 0; i < 16; ++i) {
            float4 v = Ep[tt + i * 16];
            s += v.x * v.x + v.y * v.y + v.z * v.z + v.w * v.w;
        }
        s += __shfl_xor(s, 8, 64);
        s += __shfl_xor(s, 4, 64);
        s += __shfl_xor(s, 2, 64);
        s += __shfl_xor(s, 1, 64);
        if (tt == 0) rsum[r] = s;
    }
    // --- stage BN(x) ---
    #pragma unroll
    for (int p = 0; p < 8; ++p) {
        int idx = t + p * 256;
        int dd = idx & 127, r = idx >> 7;
        float sc = g[dd] / sqrtf(var[dd] + 1e-5f);
        xb[r][dd] = (x[(size_t)(row0 + r) * D_ + dd] - mean[dd]) * sc + beta[dd];
    }
    __syncthreads();
    if (t < 16) {
        float rv = 1.0f / sqrtf(rsum[t]);
        rnS[t] = rv;
        rn_out[row0 + t] = rv;
    }
    __syncthreads();
    int j = t & 127, half = t >> 7;
    float acc1[8], acc2[8];
    #pragma unroll
    for (int r = 0; r < 8; ++r) { acc1[r] = 0.f; acc2[r] = 0.f; }
    #pragma unroll 4
    for (int dd = 0; dd < 128; ++dd) {
        float w1 = W_in[dd * 256 + j];
        float w2 = W_in[dd * 256 + 128 + j];
        #pragma unroll
        for (int r = 0; r < 8; ++r) {
            float xv = xb[half * 8 + r][dd];
            acc1[r] = fmaf(xv, w1, acc1[r]);
            acc2[r] = fmaf(xv, w2, acc2[r]);
        }
    }
    float b1 = b_in[j], b2 = b_in[128 + j];
    bf16x8 hv, lv;
    #pragma unroll
    for (int r = 0; r < 8; ++r) {
        int rr = half * 8 + r;
        float x1 = acc1[r] + b1;
        float z  = acc2[r] + b2;
        float sig = 1.0f / (1.0f + __expf(-z));
        float uv = rnS[rr] * x1 * z * sig;
        unsigned short h = f2bf(uv);
        hv[r] = (short)h;
        lv[r] = (short)f2bf(uv - bf2f(h));
    }
    int b = row0 >> 10;
    int l0 = (row0 & 1023) + half * 8;
    size_t off = bswz(b, l0, j);
    *(bf16x8*)&uswH[off] = hv;
    *(bf16x8*)&uswL[off] = lv;
}

// ---------------------------------------------------------------------------
// Shared staging macros for the two GEMM kernels (same local names in both).
// B glds: 2 ct-sections, 8 per wave, coalesced 1KB each, into buffer `nb`.
// ---------------------------------------------------------------------------
#define STAGE_B(itS, nb)                                                        \
    _Pragma("unroll")                                                           \
    for (int j2 = 0; j2 < 8; ++j2) {                                            \
        int s = wave + j2 * 4;           /* [0,32) */                           \
        int cts = s >> 4, s2 = s & 15;                                          \
        int qq = s2 & 3, nh = (s2 >> 2) & 1, hl = s2 >> 3;                      \
        size_t src0 = (size_t)((itS) * 2 + cts) * 4096;                         \
        const unsigned short* src =                                             \
            (hl ? BbL : BbH) + src0 + ((size_t)qq * 128 + nh * 64 + lane) * 8;  \
        unsigned short* dst =                                                   \
            (hl ? &sBl[nb][cts][0] : &sBh[nb][cts][0]) + qq * 1032 + nh * 512;  \
        __builtin_amdgcn_global_load_lds((gu32*)src, (lu32*)dst, 16, 0, 0);     \
    }

// k_g1 A write: one dword per chunk (c-pairs {2jj,2jj+1} and +32)
#define G1_WRITE_A(nb, v0, v1, v2, v3)                                           \
    {                                                                            \
        unsigned short h0 = f2bf(v0), h1 = f2bf(v1);                             \
        unsigned short l0 = f2bf((v0) - bf2f(h0)), l1 = f2bf((v1) - bf2f(h1));   \
        *(unsigned int*)&sAh[nb][0][aoff] = (unsigned)h0 | ((unsigned)h1 << 16); \
        *(unsigned int*)&sAl[nb][0][aoff] = (unsigned)l0 | ((unsigned)l1 << 16); \
        unsigned short h2 = f2bf(v2), h3 = f2bf(v3);                             \
        unsigned short l2 = f2bf((v2) - bf2f(h2)), l3 = f2bf((v3) - bf2f(h3));   \
        *(unsigned int*)&sAh[nb][1][aoff] = (unsigned)h2 | ((unsigned)h3 << 16); \
        *(unsigned int*)&sAl[nb][1][aoff] = (unsigned)l2 | ((unsigned)l3 << 16); \
    }

// ---------------------------------------------------------------------------
// k_g1: GEMM1 (QTX = E^T @ u', tile 16k x 128d, BK=64, full K) + gepi epilogue
// -> writes Gsw. Grid = 64 ktiles * 8 b = 512 blocks -> 2 blocks/CU.
// R11: double-buffered LDS + single raw s_barrier per iter, post-compute
// vmcnt drain. Next-iter A loads + B glds issue BEFORE the MFMA phase so
// L2/HBM latency hides under compute; the only drain is after the MFMAs.
// LDS = 76.4 KB (Gs aliased onto sBh) -> still 2 blocks/CU.
// ---------------------------------------------------------------------------
__global__ __launch_bounds__(256) void k_g1(
    const float* __restrict__ E,
    const unsigned short* __restrict__ BH, const unsigned short* __restrict__ BL,
    const float* __restrict__ EigVals, const float* __restrict__ par,
    unsigned short* __restrict__ GswH, unsigned short* __restrict__ GswL) {
    __shared__ alignas(16) unsigned short sAh[2][2][640], sAl[2][2][640];
    __shared__ alignas(16) unsigned short sBh[2][2][4128], sBl[2][2][4128];
    __shared__ float evS[16];
    int bx = blockIdx.x;
    int b = bx & 7;
    int m0 = (bx >> 3) * 16;                 // k-tile base (64 tiles)
    const float* Ab = E + (size_t)b * (1024 * 1024);
    const unsigned short* BbH = BH + (size_t)b * 131072;
    const unsigned short* BbL = BL + (size_t)b * 131072;
    int t = threadIdx.x;
    int wave = t >> 6, lane = t & 63;
    int fr = lane & 15, q = lane >> 4;
    int wn = wave * 32;
    // A staging: thread t handles m=am, c-pairs {2jj,2jj+1} (chunk0) and +32 (chunk1)
    int am = t & 15, jj = t >> 4;            // jj in [0,16)
    int ag = jj >> 2;                        // 8-short group within chunk
    int arot = (ag + (am >> 3)) & 3;
    int aoff = am * 40 + arot * 8 + ((2 * jj) & 7);
    if (t < 16) evS[t] = 1.0f - EigVals[b * 1024 + m0 + t];
    f32x4 acc[2];
    acc[0] = (f32x4){0.f, 0.f, 0.f, 0.f};
    acc[1] = (f32x4){0.f, 0.f, 0.f, 0.f};

    // ---- prologue: stage it=0 into buffer 0 ----
    {
        float v0 = Ab[(size_t)(2 * jj) * 1024 + m0 + am];
        float v1 = Ab[(size_t)(2 * jj + 1) * 1024 + m0 + am];
        float v2 = Ab[(size_t)(32 + 2 * jj) * 1024 + m0 + am];
        float v3 = Ab[(size_t)(32 + 2 * jj + 1) * 1024 + m0 + am];
        STAGE_B(0, 0);
        G1_WRITE_A(0, v0, v1, v2, v3);
        asm volatile("s_waitcnt vmcnt(0) lgkmcnt(0)" ::: "memory");
        __builtin_amdgcn_s_barrier();
    }

    #pragma unroll 2
    for (int it = 0; it < NIT_; ++it) {
        int buf = it & 1, nb = buf ^ 1;
        float v0 = 0.f, v1 = 0.f, v2 = 0.f, v3 = 0.f;
        if (it + 1 < NIT_) {
            int cb = (it + 1) * 64;
            // ---- next-iter A loads (regs) + B glds (into buf nb) ----
            v0 = Ab[(size_t)(cb + 2 * jj) * 1024 + m0 + am];
            v1 = Ab[(size_t)(cb + 2 * jj + 1) * 1024 + m0 + am];
            v2 = Ab[(size_t)(cb + 32 + 2 * jj) * 1024 + m0 + am];
            v3 = Ab[(size_t)(cb + 32 + 2 * jj + 1) * 1024 + m0 + am];
            STAGE_B(it + 1, nb);
        }
        // ---- compute on buf: 2 k-chunks x 6 MFMA ----
        __builtin_amdgcn_s_setprio(1);
        #pragma unroll
        for (int ks = 0; ks < 2; ++ks) {
            bf16x8 ah, al, bh[2], bl[2];
            {
                int p = (q + (fr >> 3)) & 3;
                int off = fr * 40 + p * 8;
                ah = *(const bf16x8*)&sAh[buf][ks][off];
                al = *(const bf16x8*)&sAl[buf][ks][off];
            }
            #pragma unroll
            for (int nt = 0; nt < 2; ++nt) {
                int off = q * 1032 + (wn + nt * 16 + fr) * 8;
                bh[nt] = *(const bf16x8*)&sBh[buf][ks][off];
                bl[nt] = *(const bf16x8*)&sBl[buf][ks][off];
            }
            #pragma unroll
            for (int nt = 0; nt < 2; ++nt) {
                acc[nt] = __builtin_amdgcn_mfma_f32_16x16x32_bf16(ah, bh[nt], acc[nt], 0, 0, 0);
                acc[nt] = __builtin_amdgcn_mfma_f32_16x16x32_bf16(ah, bl[nt], acc[nt], 0, 0, 0);
                acc[nt] = __builtin_amdgcn_mfma_f32_16x16x32_bf16(al, bh[nt], acc[nt], 0, 0, 0);
            }
        }
        __builtin_amdgcn_s_setprio(0);
        // ---- convert + ds_write next A (loads long landed; hides under MFMA) ----
        if (it + 1 < NIT_) G1_WRITE_A(nb, v0, v1, v2, v3);
        // ---- single publish barrier: my glds + ds_writes into nb are done;
        //      my ds_reads of buf are done (safe to overwrite next iter) ----
        asm volatile("s_waitcnt vmcnt(0) lgkmcnt(0)" ::: "memory");
        __builtin_amdgcn_s_barrier();
    }

    // ---- epilogue phase 1: dump raw QTX into Gs (aliased onto dead sBh) ----
    float (*Gs)[132] = (float (*)[132])(&sBh[0][0][0]);
    #pragma unroll
    for (int nt = 0; nt < 2; ++nt) {
        int col = wn + nt * 16 + fr;
        #pragma unroll
        for (int r = 0; r < 4; ++r)
            Gs[q * 4 + r][col] = acc[nt][r];
    }
    __syncthreads();
    // ---- phase 2: Gs *= w(ev,col); par from global (L2-hot 24 KB) ----
    {
        int col = t & 127, rowg = t >> 7;    // 8 rows each
        float arr[S_], aii[S_], ccc[S_];
        #pragma unroll
        for (int ss = 0; ss < S_; ++ss) {
            arr[ss] = par[ss * D_ + col];
            aii[ss] = par[DS_ + ss * D_ + col];
            ccc[ss] = par[2 * DS_ + ss * D_ + col];
        }
        #pragma unroll
        for (int i = 0; i < 8; ++i) {
            int row = rowg * 8 + i;
            float ev = evS[row];
            float w = 0.f;
            #pragma unroll
            for (int ss = 0; ss < S_; ++ss) {
                float a = ev * arr[ss], bi = ev * aii[ss];
                float oma = 1.0f - a;            // exact (Sterbenz), a in [0.5,1]
                float b2 = bi * bi;
                float num = fmaf(a, oma, -b2);
                float den = fmaf(oma, oma, b2);  // no cancellation
                float rr = __builtin_amdgcn_rcpf(den);
                rr = rr * (2.0f - den * rr);
                w = fmaf(ccc[ss], num * rr, w);
            }
            Gs[row][col] *= w;
        }
    }
    __syncthreads();
    // ---- phase 3: swizzled bf16 hi/lo write-out (16 rows = half a ct) ----
    {
        int d = t & 127, kg = t >> 7;        // kg in {0,1}: rows kg*8..+8
        bf16x8 hv, lv;
        #pragma unroll
        for (int i = 0; i < 8; ++i) {
            float v = Gs[kg * 8 + i][d];
            unsigned short h = f2bf(v);
            hv[i] = (short)h;
            lv[i] = (short)f2bf(v - bf2f(h));
        }
        int ct = m0 >> 5;
        int qsel = ((m0 >> 3) & 2) + kg;     // quarter within the ct
        size_t off = (((size_t)(b * 32 + ct) * 4 + qsel) * 128 + d) * 8;
        *(bf16x8*)&GswH[off] = hv;
        *(bf16x8*)&GswL[off] = lv;
    }
}

// ---------------------------------------------------------------------------
// k_g2: GEMM2 (yssm = E @ G, tile 16l x 128d, BK=64) + rn/silu/out-proj
// epilogue -> writes y. Grid = 512 blocks -> 2 blocks/CU.
// Same R11 single-barrier double-buffered pipeline as k_g1.
// ---------------------------------------------------------------------------
__global__ __launch_bounds__(256) void k_g2(
    const float* __restrict__ E,
    const unsigned short* __restrict__ BH, const unsigned short* __restrict__ BL,
    const float* __restrict__ rn, const float* __restrict__ W_out,
    const float* __restrict__ b_out, float* __restrict__ y) {
    __shared__ alignas(16) unsigned short sAh[2][2][640], sAl[2][2][640];
    __shared__ alignas(16) unsigned short sBh[2][2][4128], sBl[2][2][4128];
    __shared__ float rnS[16];
    int bx = blockIdx.x;
    int b = bx & 7;
    int m0 = (bx >> 3) * 16;                 // l-tile base
    const float* Ab = E + (size_t)b * (1024 * 1024);
    const unsigned short* BbH = BH + (size_t)b * 131072;
    const unsigned short* BbL = BL + (size_t)b * 131072;
    int t = threadIdx.x;
    int wave = t >> 6, lane = t & 63;
    int fr = lane & 15, q = lane >> 4;
    int wn = wave * 32;
    // A staging: thread t loads E[m0+am][cb + 4*(t&15) .. +4] (float4, row-major)
    int am = t >> 4, c4 = (t & 15) * 4;      // c4 in [0,64)
    int chunk = c4 >> 5, cw = c4 & 31;       // within-chunk offset {0,4,...,28}
    int ag = cw >> 3;
    int arot = (ag + (am >> 3)) & 3;
    int aoff = am * 40 + arot * 8 + (cw & 7);
    if (t < 16) rnS[t] = rn[b * 1024 + m0 + t];
    f32x4 acc[2];
    acc[0] = (f32x4){0.f, 0.f, 0.f, 0.f};
    acc[1] = (f32x4){0.f, 0.f, 0.f, 0.f};

#define G2_WRITE_A(nb, va)                                                       \
    {                                                                            \
        unsigned short h0 = f2bf((va).x), h1 = f2bf((va).y);                     \
        unsigned short h2 = f2bf((va).z), h3 = f2bf((va).w);                     \
        unsigned short l0 = f2bf((va).x - bf2f(h0)), l1 = f2bf((va).y - bf2f(h1));\
        unsigned short l2 = f2bf((va).z - bf2f(h2)), l3 = f2bf((va).w - bf2f(h3));\
        *(uint2*)&sAh[nb][chunk][aoff] =                                         \
            (uint2){(unsigned)h0 | ((unsigned)h1 << 16),                         \
                    (unsigned)h2 | ((unsigned)h3 << 16)};                        \
        *(uint2*)&sAl[nb][chunk][aoff] =                                         \
            (uint2){(unsigned)l0 | ((unsigned)l1 << 16),                         \
                    (unsigned)l2 | ((unsigned)l3 << 16)};                        \
    }

    // ---- prologue: stage it=0 into buffer 0 ----
    {
        float4 va = *(const float4*)&Ab[(size_t)(m0 + am) * 1024 + c4];
        STAGE_B(0, 0);
        G2_WRITE_A(0, va);
        asm volatile("s_waitcnt vmcnt(0) lgkmcnt(0)" ::: "memory");
        __builtin_amdgcn_s_barrier();
    }

    #pragma unroll 2
    for (int it = 0; it < NIT_; ++it) {
        int buf = it & 1, nb = buf ^ 1;
        float4 va = (float4){0.f, 0.f, 0.f, 0.f};
        if (it + 1 < NIT_) {
            int cb = (it + 1) * 64;
            va = *(const float4*)&Ab[(size_t)(m0 + am) * 1024 + cb + c4];
            STAGE_B(it + 1, nb);
        }
        // ---- compute on buf: 2 k-chunks x 6 MFMA ----
        __builtin_amdgcn_s_setprio(1);
        #pragma unroll
        for (int ks = 0; ks < 2; ++ks) {
            bf16x8 ah, al, bh[2], bl[2];
            {
                int p = (q + (fr >> 3)) & 3;
                int off = fr * 40 + p * 8;
                ah = *(const bf16x8*)&sAh[buf][ks][off];
                al = *(const bf16x8*)&sAl[buf][ks][off];
            }
            #pragma unroll
            for (int nt = 0; nt < 2; ++nt) {
                int off = q * 1032 + (wn + nt * 16 + fr) * 8;
                bh[nt] = *(const bf16x8*)&sBh[buf][ks][off];
                bl[nt] = *(const bf16x8*)&sBl[buf][ks][off];
            }
            #pragma unroll
            for (int nt = 0; nt < 2; ++nt) {
                acc[nt] = __builtin_amdgcn_mfma_f32_16x16x32_bf16(ah, bh[nt], acc[nt], 0, 0, 0);
                acc[nt] = __builtin_amdgcn_mfma_f32_16x16x32_bf16(ah, bl[nt], acc[nt], 0, 0, 0);
                acc[nt] = __builtin_amdgcn_mfma_f32_16x16x32_bf16(al, bh[nt], acc[nt], 0, 0, 0);
            }
        }
        __builtin_amdgcn_s_setprio(0);
        if (it + 1 < NIT_) G2_WRITE_A(nb, va);
        asm volatile("s_waitcnt vmcnt(0) lgkmcnt(0)" ::: "memory");
        __builtin_amdgcn_s_barrier();
    }

    // ---- fused epilogue: Ys = silu(yssm*rn) (Ys aliased onto dead sBh) ----
    float (*Ys)[132] = (float (*)[132])(&sBh[0][0][0]);
    #pragma unroll
    for (int nt = 0; nt < 2; ++nt) {
        int col = wn + nt * 16 + fr;
        #pragma unroll
        for (int r = 0; r < 4; ++r) {
            int row = q * 4 + r;
            float v = acc[nt][r] * rnS[row];
            float sig = 1.0f / (1.0f + __expf(-v));
            Ys[row][col] = v * sig;
        }
    }
    __syncthreads();
    // ---- out-proj: y = Ys @ W_out + b_out ----
    int j = t & 127, h = t >> 7;             // h in {0,1}: 8 rows each
    float a2[8];
    #pragma unroll
    for (int r = 0; r < 8; ++r) a2[r] = 0.f;
    for (int dd = 0; dd < 128; dd += 4) {
        float w0 = W_out[(dd + 0) * 128 + j];
        float w1 = W_out[(dd + 1) * 128 + j];
        float w2 = W_out[(dd + 2) * 128 + j];
        float w3 = W_out[(dd + 3) * 128 + j];
        #pragma unroll
        for (int r = 0; r < 8; ++r) {
            float4 yv = *(float4*)&Ys[h * 8 + r][dd];
            a2[r] = fmaf(yv.x, w0, a2[r]);
            a2[r] = fmaf(yv.y, w1, a2[r]);
            a2[r] = fmaf(yv.z, w2, a2[r]);
            a2[r] = fmaf(yv.w, w3, a2[r]);
        }
    }
    float bo = b_out[j];
    #pragma unroll
    for (int r = 0; r < 8; ++r)
        y[((size_t)b * 1024 + m0 + h * 8 + r) * 128 + j] = a2[r] + bo;
}

// ---------------------------------------------------------------------------
extern "C" void kernel_launch(void* const* d_in, const int* in_sizes, int n_in,
                              void* d_out, int out_size, void* d_ws, size_t ws_size,
                              hipStream_t stream) {
    const float* x          = (const float*)d_in[0];
    const float* EigVecs    = (const float*)d_in[2];
    const float* EigVals    = (const float*)d_in[3];
    const float* bn_gamma   = (const float*)d_in[4];
    const float* bn_beta    = (const float*)d_in[5];
    const float* bn_mean    = (const float*)d_in[6];
    const float* bn_var     = (const float*)d_in[7];
    const float* W_in       = (const float*)d_in[8];
    const float* b_in       = (const float*)d_in[9];
    const float* log_Delta  = (const float*)d_in[10];
    const float* Bp         = (const float*)d_in[11];
    const float* Cp         = (const float*)d_in[12];
    const float* log_A_real = (const float*)d_in[13];
    const float* A_imag     = (const float*)d_in[14];
    const float* W_out      = (const float*)d_in[15];
    const float* b_out      = (const float*)d_in[16];

    float* y = (float*)d_out;
    char* w = (char*)d_ws;
    float* rn            = (float*)(w);                       // 32 KB
    float* par           = (float*)(w + 32768);               // 24 KB
    unsigned short* uswH = (unsigned short*)(w + 65536);      // 2 MB each
    unsigned short* uswL = (unsigned short*)(w + 65536 + (1u << 21));
    unsigned short* GswH = (unsigned short*)(w + 65536 + 2 * (1u << 21));
    unsigned short* GswL = (unsigned short*)(w + 65536 + 3 * (1u << 21));

    k_pre<<<dim3(B_ * L_ / 16), dim3(256), 0, stream>>>(
        EigVecs, x, bn_gamma, bn_beta, bn_mean, bn_var, W_in, b_in,
        log_Delta, Bp, Cp, log_A_real, A_imag, rn, par, uswH, uswL);
    k_g1<<<dim3(512), dim3(256), 0, stream>>>(
        EigVecs, uswH, uswL, EigVals, par, GswH, GswL);
    k_g2<<<dim3(512), dim3(256), 0, stream>>>(
        EigVecs, GswH, GswL, rn, W_out, b_out, y);
}

// Round 2
// 167.175 us; speedup vs baseline: 1.0300x; 1.0038x over previous
//
#include <hip/hip_runtime.h>
#include <math.h>

#define B_ 8
#define L_ 1024
#define K_ 1024
#define D_ 128
#define S_ 16
#define DS_ (D_ * S_)
#define NIT_ 16          // full contraction, BK=64

typedef short bf16x8 __attribute__((ext_vector_type(8)));
typedef float f32x4 __attribute__((ext_vector_type(4)));

__device__ inline unsigned short f2bf(float f) {
    unsigned int u = __float_as_uint(f);
    u = (u + 0x7fffu + ((u >> 16) & 1u)) >> 16;   // RNE
    return (unsigned short)u;
}
__device__ inline float bf2f(unsigned short h) {
    return __uint_as_float(((unsigned int)h) << 16);
}

// B operands (u', G) stored PRE-SWIZZLED in glds consumption order:
// idx = ((((b*32 + ct)*4 + q)*128 + n)*8 + i), c = ct*32 + q*8 + i.
__device__ inline size_t bswz(int b, int c, int n) {
    return ((((size_t)b * 32 + (c >> 5)) * 4 + ((c >> 3) & 3)) * 128 + n) * 8;
}

// ---------------------------------------------------------------------------
// Fused: params (blocks 0-7) + rownorm + BN + in-proj + swizzled bf16 hi/lo u.
// 16 rows/block, 512 blocks.  (unchanged)
// ---------------------------------------------------------------------------
__global__ __launch_bounds__(256) void k_pre(
    const float* __restrict__ E, const float* __restrict__ x,
    const float* __restrict__ g, const float* __restrict__ beta,
    const float* __restrict__ mean, const float* __restrict__ var,
    const float* __restrict__ W_in, const float* __restrict__ b_in,
    const float* __restrict__ log_Delta, const float* __restrict__ Bp,
    const float* __restrict__ Cp, const float* __restrict__ log_A_real,
    const float* __restrict__ A_imag,
    float* __restrict__ rn_out, float* __restrict__ par,
    unsigned short* __restrict__ uswH, unsigned short* __restrict__ uswL) {
    __shared__ float xb[16][128];
    __shared__ float rsum[16];
    __shared__ float rnS[16];
    int bx = blockIdx.x;
    int row0 = bx * 16;
    int t = threadIdx.x;
    // --- params (double precision), spread over blocks 0-7 ---
    if (bx < 8) {
        int i = bx * 256 + t;                // i = d*S + s
        int d = i >> 4, s = i & 15;
        double delta = exp((double)log_Delta[d]);
        double Are = -exp((double)log_A_real[i]);
        double Aim = (double)A_imag[i];
        double mag = exp(-1e-3 + delta * Are);
        double ang = delta * Aim;
        int o = s * D_ + d;
        par[o]           = (float)(mag * cos(ang));
        par[DS_ + o]     = (float)(mag * sin(ang));
        par[2 * DS_ + o] = (float)(delta * (double)Bp[i] * (double)Cp[i]);
    }
    // --- row norms: 16 threads per row ---
    {
        int r = t >> 4, tt = t & 15;
        const float4* Ep = (const float4*)(E + (size_t)(row0 + r) * K_);
        float s = 0.f;
        #pragma unroll
        for (int i = 0; i < 16; ++i) {
            float4 v = Ep[tt + i * 16];
            s += v.x * v.x + v.y * v.y + v.z * v.z + v.w * v.w;
        }
        s += __shfl_xor(s, 8, 64);
        s += __shfl_xor(s, 4, 64);
        s += __shfl_xor(s, 2, 64);
        s += __shfl_xor(s, 1, 64);
        if (tt == 0) rsum[r] = s;
    }
    // --- stage BN(x) ---
    #pragma unroll
    for (int p = 0; p < 8; ++p) {
        int idx = t + p * 256;
        int dd = idx & 127, r = idx >> 7;
        float sc = g[dd] / sqrtf(var[dd] + 1e-5f);
        xb[r][dd] = (x[(size_t)(row0 + r) * D_ + dd] - mean[dd]) * sc + beta[dd];
    }
    __syncthreads();
    if (t < 16) {
        float rv = 1.0f / sqrtf(rsum[t]);
        rnS[t] = rv;
        rn_out[row0 + t] = rv;
    }
    __syncthreads();
    int j = t & 127, half = t >> 7;
    float acc1[8], acc2[8];
    #pragma unroll
    for (int r = 0; r < 8; ++r) { acc1[r] = 0.f; acc2[r] = 0.f; }
    #pragma unroll 4
    for (int dd = 0; dd < 128; ++dd) {
        float w1 = W_in[dd * 256 + j];
        float w2 = W_in[dd * 256 + 128 + j];
        #pragma unroll
        for (int r = 0; r < 8; ++r) {
            float xv = xb[half * 8 + r][dd];
            acc1[r] = fmaf(xv, w1, acc1[r]);
            acc2[r] = fmaf(xv, w2, acc2[r]);
        }
    }
    float b1 = b_in[j], b2 = b_in[128 + j];
    bf16x8 hv, lv;
    #pragma unroll
    for (int r = 0; r < 8; ++r) {
        int rr = half * 8 + r;
        float x1 = acc1[r] + b1;
        float z  = acc2[r] + b2;
        float sig = 1.0f / (1.0f + __expf(-z));
        float uv = rnS[rr] * x1 * z * sig;
        unsigned short h = f2bf(uv);
        hv[r] = (short)h;
        lv[r] = (short)f2bf(uv - bf2f(h));
    }
    int b = row0 >> 10;
    int l0 = (row0 & 1023) + half * 8;
    size_t off = bswz(b, l0, j);
    *(bf16x8*)&uswH[off] = hv;
    *(bf16x8*)&uswL[off] = lv;
}

// ---------------------------------------------------------------------------
// R12: reg-staged B at prefetch distance 2 (global->reg iter it+2, reg->LDS
// ds_write iter it+1). No global_load_lds: LDS publish needs only lgkmcnt(0)
// + ONE barrier per iteration; vmem latency is covered by a full iteration
// and drained by compiler-inserted counted vmcnt at the register use.
// LDS unchanged (2-buffer, 76.4 KB) -> 2 blocks/CU preserved.
//
// Per-iter reg sets: issue into set (it&1), consume set (it&1)^1.
// B slab per tile: 8192 shorts per array (H,L); granule g = t + k*256 (16B),
// LDS image identical to the old glds layout:
//   lds_byte(g) = (g>>9)*8256 + ((g>>7)&3)*2064 + (g&127)*16.
// ---------------------------------------------------------------------------
#define LOAD_B(s, tl)                                                     \
    {                                                                     \
        const bf16x8* pH = (const bf16x8*)(BbH + (size_t)(tl) * 8192);    \
        const bf16x8* pL = (const bf16x8*)(BbL + (size_t)(tl) * 8192);    \
        _Pragma("unroll")                                                 \
        for (int k = 0; k < 4; ++k) {                                     \
            rBH[s][k] = pH[t + k * 256];                                  \
            rBL[s][k] = pL[t + k * 256];                                  \
        }                                                                 \
    }
#define WRITE_B(s, nb)                                                    \
    {                                                                     \
        char* dH = (char*)&sBh[nb][0][0];                                 \
        char* dL = (char*)&sBl[nb][0][0];                                 \
        _Pragma("unroll")                                                 \
        for (int k = 0; k < 4; ++k) {                                     \
            *(bf16x8*)(dH + ldsb[k]) = rBH[s][k];                         \
            *(bf16x8*)(dL + ldsb[k]) = rBL[s][k];                         \
        }                                                                 \
    }

// k_g1 A write: one dword per chunk (c-pairs {2jj,2jj+1} and +32)
#define G1_WRITE_A(nb, v0, v1, v2, v3)                                           \
    {                                                                            \
        unsigned short h0 = f2bf(v0), h1 = f2bf(v1);                             \
        unsigned short l0 = f2bf((v0) - bf2f(h0)), l1 = f2bf((v1) - bf2f(h1));   \
        *(unsigned int*)&sAh[nb][0][aoff] = (unsigned)h0 | ((unsigned)h1 << 16); \
        *(unsigned int*)&sAl[nb][0][aoff] = (unsigned)l0 | ((unsigned)l1 << 16); \
        unsigned short h2 = f2bf(v2), h3 = f2bf(v3);                             \
        unsigned short l2 = f2bf((v2) - bf2f(h2)), l3 = f2bf((v3) - bf2f(h3));   \
        *(unsigned int*)&sAh[nb][1][aoff] = (unsigned)h2 | ((unsigned)h3 << 16); \
        *(unsigned int*)&sAl[nb][1][aoff] = (unsigned)l2 | ((unsigned)l3 << 16); \
    }

#define G1_LOAD_A(s, tl)                                                  \
    {                                                                     \
        int cb_ = (tl) * 64;                                              \
        rA[s][0] = Ab[(size_t)(cb_ + 2 * jj) * 1024 + m0 + am];           \
        rA[s][1] = Ab[(size_t)(cb_ + 2 * jj + 1) * 1024 + m0 + am];       \
        rA[s][2] = Ab[(size_t)(cb_ + 32 + 2 * jj) * 1024 + m0 + am];      \
        rA[s][3] = Ab[(size_t)(cb_ + 32 + 2 * jj + 1) * 1024 + m0 + am];  \
    }

__global__ __launch_bounds__(256, 2) void k_g1(
    const float* __restrict__ E,
    const unsigned short* __restrict__ BH, const unsigned short* __restrict__ BL,
    const float* __restrict__ EigVals, const float* __restrict__ par,
    unsigned short* __restrict__ GswH, unsigned short* __restrict__ GswL) {
    __shared__ alignas(16) unsigned short sAh[2][2][640], sAl[2][2][640];
    __shared__ alignas(16) unsigned short sBh[2][2][4128], sBl[2][2][4128];
    __shared__ float evS[16];
    int bx = blockIdx.x;
    int b = bx & 7;
    int m0 = (bx >> 3) * 16;                 // k-tile base (64 tiles)
    const float* Ab = E + (size_t)b * (1024 * 1024);
    const unsigned short* BbH = BH + (size_t)b * 131072;
    const unsigned short* BbL = BL + (size_t)b * 131072;
    int t = threadIdx.x;
    int wave = t >> 6, lane = t & 63;
    int fr = lane & 15, q = lane >> 4;
    int wn = wave * 32;
    // A staging: thread t handles m=am, c-pairs {2jj,2jj+1} (chunk0) and +32 (chunk1)
    int am = t & 15, jj = t >> 4;            // jj in [0,16)
    int ag = jj >> 2;                        // 8-short group within chunk
    int arot = (ag + (am >> 3)) & 3;
    int aoff = am * 40 + arot * 8 + ((2 * jj) & 7);
    if (t < 16) evS[t] = 1.0f - EigVals[b * 1024 + m0 + t];
    unsigned ldsb[4];
    #pragma unroll
    for (int k = 0; k < 4; ++k) {
        int gg = t + k * 256;
        ldsb[k] = (unsigned)((gg >> 9) * 8256 + ((gg >> 7) & 3) * 2064 + (gg & 127) * 16);
    }
    bf16x8 rBH[2][4], rBL[2][4];
    float rA[2][4];
    f32x4 acc[2];
    acc[0] = (f32x4){0.f, 0.f, 0.f, 0.f};
    acc[1] = (f32x4){0.f, 0.f, 0.f, 0.f};

    // ---- prologue: L0 -> set0 -> buf0; L1 -> set1 (stays in regs) ----
    G1_LOAD_A(0, 0); LOAD_B(0, 0);
    G1_LOAD_A(1, 1); LOAD_B(1, 1);
    G1_WRITE_A(0, rA[0][0], rA[0][1], rA[0][2], rA[0][3]);
    WRITE_B(0, 0);
    asm volatile("s_waitcnt lgkmcnt(0)" ::: "memory");

    #pragma unroll 2
    for (int it = 0; it < NIT_; ++it) {
        int buf = it & 1, nb = buf ^ 1;
        int sI = it & 1, sC = sI ^ 1;        // issue / consume reg sets
        if (it + 2 < NIT_) { G1_LOAD_A(sI, it + 2); LOAD_B(sI, it + 2); }
        asm volatile("" ::: "memory");
        __builtin_amdgcn_s_barrier();        // publishes buf (writes + lgkm drained pre-barrier)
        asm volatile("" ::: "memory");
        // ---- compute on buf: 2 k-chunks x 6 MFMA ----
        __builtin_amdgcn_s_setprio(1);
        #pragma unroll
        for (int ks = 0; ks < 2; ++ks) {
            bf16x8 ah, al, bh[2], bl[2];
            {
                int p = (q + (fr >> 3)) & 3;
                int off = fr * 40 + p * 8;
                ah = *(const bf16x8*)&sAh[buf][ks][off];
                al = *(const bf16x8*)&sAl[buf][ks][off];
            }
            #pragma unroll
            for (int nt = 0; nt < 2; ++nt) {
                int off = q * 1032 + (wn + nt * 16 + fr) * 8;
                bh[nt] = *(const bf16x8*)&sBh[buf][ks][off];
                bl[nt] = *(const bf16x8*)&sBl[buf][ks][off];
            }
            #pragma unroll
            for (int nt = 0; nt < 2; ++nt) {
                acc[nt] = __builtin_amdgcn_mfma_f32_16x16x32_bf16(ah, bh[nt], acc[nt], 0, 0, 0);
                acc[nt] = __builtin_amdgcn_mfma_f32_16x16x32_bf16(ah, bl[nt], acc[nt], 0, 0, 0);
                acc[nt] = __builtin_amdgcn_mfma_f32_16x16x32_bf16(al, bh[nt], acc[nt], 0, 0, 0);
            }
        }
        __builtin_amdgcn_s_setprio(0);
        // ---- stage tile it+1 into nb (reg consumption: compiler counted-vmcnt;
        //      loads got a full iteration of cover) ----
        if (it + 1 < NIT_) {
            G1_WRITE_A(nb, rA[sC][0], rA[sC][1], rA[sC][2], rA[sC][3]);
            WRITE_B(sC, nb);
            asm volatile("s_waitcnt lgkmcnt(0)" ::: "memory");
        }
    }

    // ---- epilogue phase 1: dump raw QTX into Gs (aliased onto dead sBh[0];
    //      disjoint from sBh[1] read by compute(15)) ----
    float (*Gs)[132] = (float (*)[132])(&sBh[0][0][0]);
    #pragma unroll
    for (int nt = 0; nt < 2; ++nt) {
        int col = wn + nt * 16 + fr;
        #pragma unroll
        for (int r = 0; r < 4; ++r)
            Gs[q * 4 + r][col] = acc[nt][r];
    }
    __syncthreads();
    // ---- phase 2: Gs *= w(ev,col); par from global (L2-hot 24 KB) ----
    {
        int col = t & 127, rowg = t >> 7;    // 8 rows each
        float arr[S_], aii[S_], ccc[S_];
        #pragma unroll
        for (int ss = 0; ss < S_; ++ss) {
            arr[ss] = par[ss * D_ + col];
            aii[ss] = par[DS_ + ss * D_ + col];
            ccc[ss] = par[2 * DS_ + ss * D_ + col];
        }
        #pragma unroll
        for (int i = 0; i < 8; ++i) {
            int row = rowg * 8 + i;
            float ev = evS[row];
            float w = 0.f;
            #pragma unroll
            for (int ss = 0; ss < S_; ++ss) {
                float a = ev * arr[ss], bi = ev * aii[ss];
                float oma = 1.0f - a;            // exact (Sterbenz), a in [0.5,1]
                float b2 = bi * bi;
                float num = fmaf(a, oma, -b2);
                float den = fmaf(oma, oma, b2);  // no cancellation
                float rr = __builtin_amdgcn_rcpf(den);
                rr = rr * (2.0f - den * rr);
                w = fmaf(ccc[ss], num * rr, w);
            }
            Gs[row][col] *= w;
        }
    }
    __syncthreads();
    // ---- phase 3: swizzled bf16 hi/lo write-out (16 rows = half a ct) ----
    {
        int d = t & 127, kg = t >> 7;        // kg in {0,1}: rows kg*8..+8
        bf16x8 hv, lv;
        #pragma unroll
        for (int i = 0; i < 8; ++i) {
            float v = Gs[kg * 8 + i][d];
            unsigned short h = f2bf(v);
            hv[i] = (short)h;
            lv[i] = (short)f2bf(v - bf2f(h));
        }
        int ct = m0 >> 5;
        int qsel = ((m0 >> 3) & 2) + kg;     // quarter within the ct
        size_t off = (((size_t)(b * 32 + ct) * 4 + qsel) * 128 + d) * 8;
        *(bf16x8*)&GswH[off] = hv;
        *(bf16x8*)&GswL[off] = lv;
    }
}

// ---------------------------------------------------------------------------
// k_g2: GEMM2 (yssm = E @ G, tile 16l x 128d, BK=64) + rn/silu/out-proj
// epilogue -> writes y. Grid = 512 blocks -> 2 blocks/CU.
// Same R12 reg-staged distance-2 pipeline as k_g1.
// ---------------------------------------------------------------------------
#define G2_WRITE_A(nb, va)                                                       \
    {                                                                            \
        unsigned short h0 = f2bf((va).x), h1 = f2bf((va).y);                     \
        unsigned short h2 = f2bf((va).z), h3 = f2bf((va).w);                     \
        unsigned short l0 = f2bf((va).x - bf2f(h0)), l1 = f2bf((va).y - bf2f(h1));\
        unsigned short l2 = f2bf((va).z - bf2f(h2)), l3 = f2bf((va).w - bf2f(h3));\
        *(uint2*)&sAh[nb][chunk][aoff] =                                         \
            (uint2){(unsigned)h0 | ((unsigned)h1 << 16),                         \
                    (unsigned)h2 | ((unsigned)h3 << 16)};                        \
        *(uint2*)&sAl[nb][chunk][aoff] =                                         \
            (uint2){(unsigned)l0 | ((unsigned)l1 << 16),                         \
                    (unsigned)l2 | ((unsigned)l3 << 16)};                        \
    }

__global__ __launch_bounds__(256, 2) void k_g2(
    const float* __restrict__ E,
    const unsigned short* __restrict__ BH, const unsigned short* __restrict__ BL,
    const float* __restrict__ rn, const float* __restrict__ W_out,
    const float* __restrict__ b_out, float* __restrict__ y) {
    __shared__ alignas(16) unsigned short sAh[2][2][640], sAl[2][2][640];
    __shared__ alignas(16) unsigned short sBh[2][2][4128], sBl[2][2][4128];
    __shared__ float rnS[16];
    int bx = blockIdx.x;
    int b = bx & 7;
    int m0 = (bx >> 3) * 16;                 // l-tile base
    const float* Ab = E + (size_t)b * (1024 * 1024);
    const unsigned short* BbH = BH + (size_t)b * 131072;
    const unsigned short* BbL = BL + (size_t)b * 131072;
    int t = threadIdx.x;
    int wave = t >> 6, lane = t & 63;
    int fr = lane & 15, q = lane >> 4;
    int wn = wave * 32;
    // A staging: thread t loads E[m0+am][cb + 4*(t&15) .. +4] (float4, row-major)
    int am = t >> 4, c4 = (t & 15) * 4;      // c4 in [0,64)
    int chunk = c4 >> 5, cw = c4 & 31;       // within-chunk offset {0,4,...,28}
    int ag = cw >> 3;
    int arot = (ag + (am >> 3)) & 3;
    int aoff = am * 40 + arot * 8 + (cw & 7);
    if (t < 16) rnS[t] = rn[b * 1024 + m0 + t];
    unsigned ldsb[4];
    #pragma unroll
    for (int k = 0; k < 4; ++k) {
        int gg = t + k * 256;
        ldsb[k] = (unsigned)((gg >> 9) * 8256 + ((gg >> 7) & 3) * 2064 + (gg & 127) * 16);
    }
    bf16x8 rBH[2][4], rBL[2][4];
    float4 rA4[2];
    f32x4 acc[2];
    acc[0] = (f32x4){0.f, 0.f, 0.f, 0.f};
    acc[1] = (f32x4){0.f, 0.f, 0.f, 0.f};

#define G2_LOAD_A(s, tl)                                                         \
    rA4[s] = *(const float4*)&Ab[(size_t)(m0 + am) * 1024 + (tl) * 64 + c4];

    // ---- prologue: L0 -> set0 -> buf0; L1 -> set1 ----
    G2_LOAD_A(0, 0); LOAD_B(0, 0);
    G2_LOAD_A(1, 1); LOAD_B(1, 1);
    G2_WRITE_A(0, rA4[0]);
    WRITE_B(0, 0);
    asm volatile("s_waitcnt lgkmcnt(0)" ::: "memory");

    #pragma unroll 2
    for (int it = 0; it < NIT_; ++it) {
        int buf = it & 1, nb = buf ^ 1;
        int sI = it & 1, sC = sI ^ 1;
        if (it + 2 < NIT_) { G2_LOAD_A(sI, it + 2); LOAD_B(sI, it + 2); }
        asm volatile("" ::: "memory");
        __builtin_amdgcn_s_barrier();
        asm volatile("" ::: "memory");
        // ---- compute on buf: 2 k-chunks x 6 MFMA ----
        __builtin_amdgcn_s_setprio(1);
        #pragma unroll
        for (int ks = 0; ks < 2; ++ks) {
            bf16x8 ah, al, bh[2], bl[2];
            {
                int p = (q + (fr >> 3)) & 3;
                int off = fr * 40 + p * 8;
                ah = *(const bf16x8*)&sAh[buf][ks][off];
                al = *(const bf16x8*)&sAl[buf][ks][off];
            }
            #pragma unroll
            for (int nt = 0; nt < 2; ++nt) {
                int off = q * 1032 + (wn + nt * 16 + fr) * 8;
                bh[nt] = *(const bf16x8*)&sBh[buf][ks][off];
                bl[nt] = *(const bf16x8*)&sBl[buf][ks][off];
            }
            #pragma unroll
            for (int nt = 0; nt < 2; ++nt) {
                acc[nt] = __builtin_amdgcn_mfma_f32_16x16x32_bf16(ah, bh[nt], acc[nt], 0, 0, 0);
                acc[nt] = __builtin_amdgcn_mfma_f32_16x16x32_bf16(ah, bl[nt], acc[nt], 0, 0, 0);
                acc[nt] = __builtin_amdgcn_mfma_f32_16x16x32_bf16(al, bh[nt], acc[nt], 0, 0, 0);
            }
        }
        __builtin_amdgcn_s_setprio(0);
        if (it + 1 < NIT_) {
            G2_WRITE_A(nb, rA4[sC]);
            WRITE_B(sC, nb);
            asm volatile("s_waitcnt lgkmcnt(0)" ::: "memory");
        }
    }

    // ---- fused epilogue: Ys = silu(yssm*rn) (Ys aliased onto dead sBh[0]) ----
    float (*Ys)[132] = (float (*)[132])(&sBh[0][0][0]);
    #pragma unroll
    for (int nt = 0; nt < 2; ++nt) {
        int col = wn + nt * 16 + fr;
        #pragma unroll
        for (int r = 0; r < 4; ++r) {
            int row = q * 4 + r;
            float v = acc[nt][r] * rnS[row];
            float sig = 1.0f / (1.0f + __expf(-v));
            Ys[row][col] = v * sig;
        }
    }
    __syncthreads();
    // ---- out-proj: y = Ys @ W_out + b_out ----
    int j = t & 127, h = t >> 7;             // h in {0,1}: 8 rows each
    float a2[8];
    #pragma unroll
    for (int r = 0; r < 8; ++r) a2[r] = 0.f;
    for (int dd = 0; dd < 128; dd += 4) {
        float w0 = W_out[(dd + 0) * 128 + j];
        float w1 = W_out[(dd + 1) * 128 + j];
        float w2 = W_out[(dd + 2) * 128 + j];
        float w3 = W_out[(dd + 3) * 128 + j];
        #pragma unroll
        for (int r = 0; r < 8; ++r) {
            float4 yv = *(float4*)&Ys[h * 8 + r][dd];
            a2[r] = fmaf(yv.x, w0, a2[r]);
            a2[r] = fmaf(yv.y, w1, a2[r]);
            a2[r] = fmaf(yv.z, w2, a2[r]);
            a2[r] = fmaf(yv.w, w3, a2[r]);
        }
    }
    float bo = b_out[j];
    #pragma unroll
    for (int r = 0; r < 8; ++r)
        y[((size_t)b * 1024 + m0 + h * 8 + r) * 128 + j] = a2[r] + bo;
}

// ---------------------------------------------------------------------------
extern "C" void kernel_launch(void* const* d_in, const int* in_sizes, int n_in,
                              void* d_out, int out_size, void* d_ws, size_t ws_size,
                              hipStream_t stream) {
    const float* x          = (const float*)d_in[0];
    const float* EigVecs    = (const float*)d_in[2];
    const float* EigVals    = (const float*)d_in[3];
    const float* bn_gamma   = (const float*)d_in[4];
    const float* bn_beta    = (const float*)d_in[5];
    const float* bn_mean    = (const float*)d_in[6];
    const float* bn_var     = (const float*)d_in[7];
    const float* W_in       = (const float*)d_in[8];
    const float* b_in       = (const float*)d_in[9];
    const float* log_Delta  = (const float*)d_in[10];
    const float* Bp         = (const float*)d_in[11];
    const float* Cp         = (const float*)d_in[12];
    const float* log_A_real = (const float*)d_in[13];
    const float* A_imag     = (const float*)d_in[14];
    const float* W_out      = (const float*)d_in[15];
    const float* b_out      = (const float*)d_in[16];

    float* y = (float*)d_out;
    char* w = (char*)d_ws;
    float* rn            = (float*)(w);                       // 32 KB
    float* par           = (float*)(w + 32768);               // 24 KB
    unsigned short* uswH = (unsigned short*)(w + 65536);      // 2 MB each
    unsigned short* uswL = (unsigned short*)(w + 65536 + (1u << 21));
    unsigned short* GswH = (unsigned short*)(w + 65536 + 2 * (1u << 21));
    unsigned short* GswL = (unsigned short*)(w + 65536 + 3 * (1u << 21));

    k_pre<<<dim3(B_ * L_ / 16), dim3(256), 0, stream>>>(
        EigVecs, x, bn_gamma, bn_beta, bn_mean, bn_var, W_in, b_in,
        log_Delta, Bp, Cp, log_A_real, A_imag, rn, par, uswH, uswL);
    k_g1<<<dim3(512), dim3(256), 0, stream>>>(
        EigVecs, uswH, uswL, EigVals, par, GswH, GswL);
    k_g2<<<dim3(512), dim3(256), 0, stream>>>(
        EigVecs, GswH, GswL, rn, W_out, b_out, y);
}